// Round 8
// baseline (665.813 us; speedup 1.0000x reference)
//
#include <hip/hip_runtime.h>

typedef short s8v __attribute__((ext_vector_type(8)));
typedef short s4v __attribute__((ext_vector_type(4)));
typedef float f4v __attribute__((ext_vector_type(4)));

typedef const __attribute__((address_space(1))) char* gp1_t;
typedef __attribute__((address_space(3))) char* lp3_t;

__device__ __forceinline__ float bf2f(short s) {
    union { unsigned u; float f; } c;
    c.u = ((unsigned)(unsigned short)s) << 16;
    return c.f;
}
__device__ __forceinline__ short f2bf(float f) {
    union { float f; unsigned u; } c; c.f = f;
    unsigned r = (c.u + 0x7FFFu + ((c.u >> 16) & 1u)) >> 16;
    return (short)r;
}
__device__ __forceinline__ s8v cvt8(const float* __restrict__ p) {
    f4v a = *(const f4v*)p;
    f4v b = *(const f4v*)(p + 4);
    s8v r;
    r[0] = f2bf(a[0]); r[1] = f2bf(a[1]); r[2] = f2bf(a[2]); r[3] = f2bf(a[3]);
    r[4] = f2bf(b[0]); r[5] = f2bf(b[1]); r[6] = f2bf(b[2]); r[7] = f2bf(b[3]);
    return r;
}

// ======================= FAST PATH (ws >= 64 MiB) =======================

__global__ __launch_bounds__(256) void cvt_x(const float* __restrict__ x,
                                             short* __restrict__ xb) {
    long i = ((long)blockIdx.x * 256 + threadIdx.x) * 8;
    *(s8v*)&xb[i] = cvt8(&x[i]);
}

// W (2048 x N fp32) -> Wt rows [obase+n][k] bf16 (ld 2048)
__global__ __launch_bounds__(256) void cvt_wt(const float* __restrict__ W,
                                              short* __restrict__ Wt,
                                              int N, int obase) {
    __shared__ __align__(16) short tile[64 * 72];
    const int kt = blockIdx.y * 64, n0 = blockIdx.x * 64;
    const int t = threadIdx.x;
    const int r = t >> 4, c4 = (t & 15) * 4;
#pragma unroll
    for (int i = 0; i < 4; i++) {
        int kr = r + i * 16;
        f4v v = *(const f4v*)&W[(long)(kt + kr) * N + n0 + c4];
#pragma unroll
        for (int j = 0; j < 4; j++) tile[(c4 + j) * 72 + kr] = f2bf(v[j]);
    }
    __syncthreads();
    const int nr = t >> 3, kc = (t & 7) * 8;
#pragma unroll
    for (int i = 0; i < 2; i++) {
        int n = nr + i * 32;
        *(s8v*)&Wt[(long)(obase + n0 + n) * 2048 + kt + kc] = *(const s8v*)&tile[n * 72 + kc];
    }
}

// m97-style GEMM: A (M x K bf16, lda), Bt (N x K bf16, ldb), C (M x N, ldc).
template <bool CF32>
__global__ __launch_bounds__(256) void gemm_bt(const short* __restrict__ A,
                                               const short* __restrict__ Bt,
                                               void* __restrict__ Cv,
                                               int K, int lda, int ldb, int ldc) {
    __shared__ __align__(16) short As[128 * 32];
    __shared__ __align__(16) short Bs[128 * 32];
    const int tid = threadIdx.x;
    const int lane = tid & 63;
    const int wave = tid >> 6;
    const int quad = lane >> 4;
    const int l15 = lane & 15;
    const int m0 = blockIdx.y * 128;
    const int n0 = blockIdx.x * 128;
    const int wm = (wave & 1) * 64;
    const int wn = (wave >> 1) * 64;

    f4v acc[4][4];
#pragma unroll
    for (int i = 0; i < 4; i++)
#pragma unroll
        for (int j = 0; j < 4; j++) acc[i][j] = (f4v){0.f, 0.f, 0.f, 0.f};

    const int s0 = wave * 64 + lane, s1 = (4 + wave) * 64 + lane;
    const short* a0 = A + (long)(m0 + (s0 >> 2)) * lda + (s0 & 3) * 8;
    const short* a1 = A + (long)(m0 + (s1 >> 2)) * lda + (s1 & 3) * 8;
    const short* b0 = Bt + (long)(n0 + (s0 >> 2)) * ldb + (s0 & 3) * 8;
    const short* b1 = Bt + (long)(n0 + (s1 >> 2)) * ldb + (s1 & 3) * 8;
    char* lA0 = (char*)As + wave * 1024;
    char* lA1 = (char*)As + (4 + wave) * 1024;
    char* lB0 = (char*)Bs + wave * 1024;
    char* lB1 = (char*)Bs + (4 + wave) * 1024;

    for (int k0 = 0; k0 < K; k0 += 32) {
        __syncthreads();
        __builtin_amdgcn_global_load_lds((gp1_t)(a0 + k0), (lp3_t)lA0, 16, 0, 0);
        __builtin_amdgcn_global_load_lds((gp1_t)(a1 + k0), (lp3_t)lA1, 16, 0, 0);
        __builtin_amdgcn_global_load_lds((gp1_t)(b0 + k0), (lp3_t)lB0, 16, 0, 0);
        __builtin_amdgcn_global_load_lds((gp1_t)(b1 + k0), (lp3_t)lB1, 16, 0, 0);
        __syncthreads();
        s8v af[4], bfr[4];
#pragma unroll
        for (int mi = 0; mi < 4; mi++)
            af[mi] = *(const s8v*)(&As[(wm + mi * 16 + l15) * 32 + quad * 8]);
#pragma unroll
        for (int ni = 0; ni < 4; ni++)
            bfr[ni] = *(const s8v*)(&Bs[(wn + ni * 16 + l15) * 32 + quad * 8]);
#pragma unroll
        for (int mi = 0; mi < 4; mi++)
#pragma unroll
            for (int ni = 0; ni < 4; ni++)
                acc[mi][ni] = __builtin_amdgcn_mfma_f32_16x16x32_bf16(af[mi], bfr[ni], acc[mi][ni], 0, 0, 0);
    }
#pragma unroll
    for (int mi = 0; mi < 4; mi++)
#pragma unroll
        for (int ni = 0; ni < 4; ni++)
#pragma unroll
            for (int r = 0; r < 4; r++) {
                int row = m0 + wm + mi * 16 + quad * 4 + r;
                int col = n0 + wn + ni * 16 + l15;
                if (CF32) ((float*)Cv)[(long)row * ldc + col] = acc[mi][ni][r];
                else      ((short*)Cv)[(long)row * ldc + col] = f2bf(acc[mi][ni][r]);
            }
}

// RoPE in-place on qkv cols [0,2560)
__global__ __launch_bounds__(256) void rope_kernel(short* __restrict__ qkv) {
    int tid = blockIdx.x * 256 + threadIdx.x;
    int p = tid % 1280;
    int row = tid / 1280;
    int head = p >> 5;
    int j = p & 31;
    int s = row & 2047;
    int c1 = head * 64 + j;
    float freq = exp2f(-(float)j * 0.4152410118609203f);
    float ang = (float)s * freq;
    float sn, cs;
    __sincosf(ang, &sn, &cs);
    long base = (long)row * 3072;
    float x1 = bf2f(qkv[base + c1]);
    float x2 = bf2f(qkv[base + c1 + 32]);
    qkv[base + c1]      = f2bf(x1 * cs - x2 * sn);
    qkv[base + c1 + 32] = f2bf(x2 * cs + x1 * sn);
}

// V transpose: qkv v-region -> Vt_g[(b*8+kvh)*64 + d][key] (ld 2048)
__global__ __launch_bounds__(256) void vtrans(const short* __restrict__ qkv,
                                              short* __restrict__ Vt_g) {
    __shared__ __align__(16) short tile[64 * 72];
    const int kt = blockIdx.x * 64;
    const int kvh = blockIdx.y;
    const int b = blockIdx.z;
    const int t = threadIdx.x;
#pragma unroll
    for (int cc = 0; cc < 2; cc++) {
        int ch = t + cc * 256;
        int key = ch >> 3, d0 = (ch & 7) * 8;
        s8v v = *(const s8v*)&qkv[(long)(b * 2048 + kt + key) * 3072 + 2560 + kvh * 64 + d0];
#pragma unroll
        for (int i = 0; i < 8; i++) tile[(d0 + i) * 72 + key] = v[i];
    }
    __syncthreads();
#pragma unroll
    for (int cc = 0; cc < 2; cc++) {
        int ch = t + cc * 256;
        int d = ch >> 3, kc = (ch & 7) * 8;
        *(s8v*)&Vt_g[(long)((b * 8 + kvh) * 64 + d) * 2048 + kt + kc] = *(const s8v*)&tile[d * 72 + kc];
    }
}

// Transpose-domain flash attention: S^T = K.Q^T, O^T += V^T.P^T.
// Wave owns 16 keys x all 64 q-rows; Q-frags and P stay in registers.
// Fixed-max exp2 softmax -> per-wave partial O/l, merged via LDS ds_add_f32.
__global__ __launch_bounds__(256) void attn3(short* __restrict__ qkv,
                                             const short* __restrict__ Vt_g) {
    __shared__ __align__(16) char smem_[46080];
    short* Qs  = (short*)smem_;               // 64*72
    short* Ks0 = (short*)(smem_ + 9216);
    short* Ks1 = (short*)(smem_ + 18432);
    short* Vt0 = (short*)(smem_ + 27648);
    short* Vt1 = (short*)(smem_ + 36864);
    float* red = (float*)smem_;               // Osum[64*66] + Lred[64] (aliases Qs+Ks0)

    const int tid = threadIdx.x;
    const int lane = tid & 63;
    const int wave = tid >> 6;
    const int quad = lane >> 4;
    const int l15 = lane & 15;
    const int b = blockIdx.z, h = blockIdx.y, kvh = h >> 2;
    const int q0 = blockIdx.x * 64;

    const long qbase = ((long)b * 2048 + q0) * 3072 + h * 64;
    const long kbase = ((long)b * 2048) * 3072 + 2048 + kvh * 64;
    const long vtbase = (long)(b * 8 + kvh) * 64 * 2048;

    // stage Q, load loop-invariant Q B-frags (B[k=d][n=qrow])
#pragma unroll
    for (int cc = 0; cc < 2; cc++) {
        int ch = tid + cc * 256;
        int r = ch >> 3, c0 = (ch & 7) * 8;
        *(s8v*)&Qs[r * 72 + c0] = *(const s8v*)&qkv[qbase + (long)r * 3072 + c0];
    }
    __syncthreads();
    s8v qf[4][2];
#pragma unroll
    for (int rb = 0; rb < 4; rb++)
#pragma unroll
        for (int hh = 0; hh < 2; hh++)
            qf[rb][hh] = *(const s8v*)&Qs[(rb * 16 + l15) * 72 + hh * 32 + quad * 8];

    f4v o[4][4];
#pragma unroll
    for (int db = 0; db < 4; db++)
#pragma unroll
        for (int rb = 0; rb < 4; rb++) o[db][rb] = (f4v){0.f, 0.f, 0.f, 0.f};
    float rs[4] = {0.f, 0.f, 0.f, 0.f};
    const float C2 = 0.18033688011112042f;  // 0.125 * log2(e)

    for (int kt = 0; kt < 2048; kt += 128) {
        __syncthreads();
#pragma unroll
        for (int cc = 0; cc < 4; cc++) {
            int ch = tid + cc * 256;         // 0..1023
            int t = ch >> 9;                 // tile 0/1
            int r = (ch >> 3) & 63;
            int c0 = (ch & 7) * 8;
            short* Kd = t ? Ks1 : Ks0;
            short* Vd = t ? Vt1 : Vt0;
            *(s8v*)&Kd[r * 72 + c0] = *(const s8v*)&qkv[kbase + (long)(kt + t * 64 + r) * 3072 + c0];
            *(s8v*)&Vd[r * 72 + c0] = *(const s8v*)&Vt_g[vtbase + (long)r * 2048 + kt + t * 64 + c0];
        }
        __syncthreads();

        s8v pf[4];
        // tile 0: S^T (16 keys x 64 rows), pack P into slots 0..3
        {
            s8v kf0 = *(const s8v*)&Ks0[(wave * 16 + l15) * 72 + quad * 8];
            s8v kf1 = *(const s8v*)&Ks0[(wave * 16 + l15) * 72 + 32 + quad * 8];
#pragma unroll
            for (int rb = 0; rb < 4; rb++) {
                f4v a = (f4v){0.f, 0.f, 0.f, 0.f};
                a = __builtin_amdgcn_mfma_f32_16x16x32_bf16(kf0, qf[rb][0], a, 0, 0, 0);
                a = __builtin_amdgcn_mfma_f32_16x16x32_bf16(kf1, qf[rb][1], a, 0, 0, 0);
#pragma unroll
                for (int r = 0; r < 4; r++) {
                    float p = exp2f(fmaf(a[r], C2, -24.0f));
                    rs[rb] += p;
                    pf[rb][r] = (short)((__float_as_uint(p) + 0x8000u) >> 16);
                }
            }
        }
        // tile 1: pack into slots 4..7
        {
            s8v kf0 = *(const s8v*)&Ks1[(wave * 16 + l15) * 72 + quad * 8];
            s8v kf1 = *(const s8v*)&Ks1[(wave * 16 + l15) * 72 + 32 + quad * 8];
#pragma unroll
            for (int rb = 0; rb < 4; rb++) {
                f4v a = (f4v){0.f, 0.f, 0.f, 0.f};
                a = __builtin_amdgcn_mfma_f32_16x16x32_bf16(kf0, qf[rb][0], a, 0, 0, 0);
                a = __builtin_amdgcn_mfma_f32_16x16x32_bf16(kf1, qf[rb][1], a, 0, 0, 0);
#pragma unroll
                for (int r = 0; r < 4; r++) {
                    float p = exp2f(fmaf(a[r], C2, -24.0f));
                    rs[rb] += p;
                    pf[rb][4 + r] = (short)((__float_as_uint(p) + 0x8000u) >> 16);
                }
            }
        }
        // PV: O^T[d][qrow] += V^T.P^T, k-slot j = tile*4 + r (keys quad*4+r of each tile)
#pragma unroll
        for (int db = 0; db < 4; db++) {
            s4v v0 = *(const s4v*)&Vt0[(db * 16 + l15) * 72 + wave * 16 + quad * 4];
            s4v v1 = *(const s4v*)&Vt1[(db * 16 + l15) * 72 + wave * 16 + quad * 4];
            s8v vf = __builtin_shufflevector(v0, v1, 0, 1, 2, 3, 4, 5, 6, 7);
#pragma unroll
            for (int rb = 0; rb < 4; rb++)
                o[db][rb] = __builtin_amdgcn_mfma_f32_16x16x32_bf16(vf, pf[rb], o[db][rb], 0, 0, 0);
        }
    }

    // cross-wave reduction of O^T and l
    __syncthreads();
    for (int i = tid; i < 4288; i += 256) red[i] = 0.f;
    __syncthreads();
#pragma unroll
    for (int rb = 0; rb < 4; rb++) {
        float v = rs[rb];
        v += __shfl_xor(v, 16);
        v += __shfl_xor(v, 32);
        if (quad == 0) atomicAdd(&red[4224 + rb * 16 + l15], v);
    }
#pragma unroll
    for (int db = 0; db < 4; db++)
#pragma unroll
        for (int rb = 0; rb < 4; rb++)
#pragma unroll
            for (int r = 0; r < 4; r++)
                atomicAdd(&red[(db * 16 + quad * 4 + r) * 66 + rb * 16 + l15], o[db][rb][r]);
    __syncthreads();
    // epilogue: out[qrow][d] = Osum[d][qrow] / l[qrow], in-place into qkv q-cols
    {
        int qrow = tid >> 2, d0 = (tid & 3) * 16;
        float inv = 1.0f / red[4224 + qrow];
        short tmp[16];
#pragma unroll
        for (int i = 0; i < 16; i++)
            tmp[i] = f2bf(red[(d0 + i) * 66 + qrow] * inv);
        long ob = ((long)b * 2048 + q0 + qrow) * 3072 + h * 64 + d0;
        *(s8v*)&qkv[ob]     = *(s8v*)&tmp[0];
        *(s8v*)&qkv[ob + 8] = *(s8v*)&tmp[8];
    }
}

// ======================= FALLBACK PATH (round-6, known-PASS) =======================

template <bool AF32, bool CF32>
__global__ __launch_bounds__(256) void gemm_bn(const void* __restrict__ Av,
                                               const float* __restrict__ B,
                                               void* __restrict__ Cv,
                                               int K, int N, int lda, int ldc) {
    __shared__ __align__(16) short As[128 * 40];
    __shared__ __align__(16) short Bs[128 * 40];
    const int tid = threadIdx.x;
    const int lane = tid & 63;
    const int wave = tid >> 6;
    const int quad = lane >> 4;
    const int l15 = lane & 15;
    const int m0 = blockIdx.y * 128;
    const int n0 = blockIdx.x * 128;
    const int wm = (wave & 1) * 64;
    const int wn = (wave >> 1) * 64;

    f4v acc[4][4];
#pragma unroll
    for (int i = 0; i < 4; i++)
#pragma unroll
        for (int j = 0; j < 4; j++) acc[i][j] = (f4v){0.f, 0.f, 0.f, 0.f};

    const int ar0 = tid >> 2, akc0 = (tid & 3) * 8;
    const int ar1 = (tid + 256) >> 2, akc1 = ((tid + 256) & 3) * 8;
    const int bk0 = tid >> 4, bnc0 = (tid & 15) * 8;
    const int bk1 = (tid + 256) >> 4, bnc1 = ((tid + 256) & 15) * 8;

    for (int k0 = 0; k0 < K; k0 += 32) {
        __syncthreads();
        if (AF32) {
            const float* A = (const float*)Av;
            *(s8v*)(&As[ar0 * 40 + akc0]) = cvt8(&A[(long)(m0 + ar0) * lda + k0 + akc0]);
            *(s8v*)(&As[ar1 * 40 + akc1]) = cvt8(&A[(long)(m0 + ar1) * lda + k0 + akc1]);
        } else {
            const short* A = (const short*)Av;
            *(s8v*)(&As[ar0 * 40 + akc0]) = *(const s8v*)(&A[(long)(m0 + ar0) * lda + k0 + akc0]);
            *(s8v*)(&As[ar1 * 40 + akc1]) = *(const s8v*)(&A[(long)(m0 + ar1) * lda + k0 + akc1]);
        }
        s8v b0 = cvt8(&B[(long)(k0 + bk0) * N + n0 + bnc0]);
        s8v b1 = cvt8(&B[(long)(k0 + bk1) * N + n0 + bnc1]);
#pragma unroll
        for (int i = 0; i < 8; i++) Bs[(bnc0 + i) * 40 + bk0] = b0[i];
#pragma unroll
        for (int i = 0; i < 8; i++) Bs[(bnc1 + i) * 40 + bk1] = b1[i];
        __syncthreads();
        s8v af[4], bfr[4];
#pragma unroll
        for (int mi = 0; mi < 4; mi++)
            af[mi] = *(const s8v*)(&As[(wm + mi * 16 + l15) * 40 + quad * 8]);
#pragma unroll
        for (int ni = 0; ni < 4; ni++)
            bfr[ni] = *(const s8v*)(&Bs[(wn + ni * 16 + l15) * 40 + quad * 8]);
#pragma unroll
        for (int mi = 0; mi < 4; mi++)
#pragma unroll
            for (int ni = 0; ni < 4; ni++)
                acc[mi][ni] = __builtin_amdgcn_mfma_f32_16x16x32_bf16(af[mi], bfr[ni], acc[mi][ni], 0, 0, 0);
    }
#pragma unroll
    for (int mi = 0; mi < 4; mi++)
#pragma unroll
        for (int ni = 0; ni < 4; ni++)
#pragma unroll
            for (int r = 0; r < 4; r++) {
                int row = m0 + wm + mi * 16 + quad * 4 + r;
                int col = n0 + wn + ni * 16 + l15;
                if (CF32) ((float*)Cv)[(long)row * ldc + col] = acc[mi][ni][r];
                else      ((short*)Cv)[(long)row * ldc + col] = f2bf(acc[mi][ni][r]);
            }
}

__global__ __launch_bounds__(256) void attn_kernel(short* __restrict__ qkv) {
    __shared__ __align__(16) short Qs[64 * 72];
    __shared__ __align__(16) short Ks[64 * 72];
    __shared__ __align__(16) short Vt[64 * 72];
    __shared__ __align__(16) short Ps[4][16 * 72];

    const int tid = threadIdx.x;
    const int lane = tid & 63;
    const int wave = tid >> 6;
    const int quad = lane >> 4;
    const int l15 = lane & 15;
    const int b = blockIdx.z;
    const int h = blockIdx.y;
    const int kvh = h >> 2;
    const int q0 = blockIdx.x * 64;

    const long qbase = ((long)b * 2048 + q0) * 3072 + h * 64;
    const long kbase = ((long)b * 2048) * 3072 + 2048 + kvh * 64;
    const long vbase = kbase + 512;

#pragma unroll
    for (int cc = 0; cc < 2; cc++) {
        int ch = tid + cc * 256;
        int r = ch >> 3, d0 = (ch & 7) * 8;
        *(s8v*)(&Qs[r * 72 + d0]) = *(const s8v*)(&qkv[qbase + (long)r * 3072 + d0]);
    }
    __syncthreads();
    s8v qf[2];
    qf[0] = *(const s8v*)(&Qs[(wave * 16 + l15) * 72 + quad * 8]);
    qf[1] = *(const s8v*)(&Qs[(wave * 16 + l15) * 72 + 32 + quad * 8]);

    float m_i[4], l_i[4];
    f4v o[4];
#pragma unroll
    for (int r = 0; r < 4; r++) { m_i[r] = -1e30f; l_i[r] = 0.0f; }
#pragma unroll
    for (int ni = 0; ni < 4; ni++) o[ni] = (f4v){0.f, 0.f, 0.f, 0.f};

    for (int kt = 0; kt < 2048; kt += 64) {
        __syncthreads();
#pragma unroll
        for (int cc = 0; cc < 2; cc++) {
            int ch = tid + cc * 256;
            int r = ch >> 3, d0 = (ch & 7) * 8;
            *(s8v*)(&Ks[r * 72 + d0]) = *(const s8v*)(&qkv[kbase + (long)(kt + r) * 3072 + d0]);
            s8v v = *(const s8v*)(&qkv[vbase + (long)(kt + r) * 3072 + d0]);
            int g = d0 >> 3;
            int chn = ((r >> 3) ^ g) * 8 + (r & 7);
#pragma unroll
            for (int i = 0; i < 8; i++) Vt[(d0 + i) * 72 + chn] = v[i];
        }
        __syncthreads();

        f4v sc[4];
#pragma unroll
        for (int ni = 0; ni < 4; ni++) {
            s8v kf0 = *(const s8v*)(&Ks[(ni * 16 + l15) * 72 + quad * 8]);
            s8v kf1 = *(const s8v*)(&Ks[(ni * 16 + l15) * 72 + 32 + quad * 8]);
            f4v a = (f4v){0.f, 0.f, 0.f, 0.f};
            a = __builtin_amdgcn_mfma_f32_16x16x32_bf16(qf[0], kf0, a, 0, 0, 0);
            a = __builtin_amdgcn_mfma_f32_16x16x32_bf16(qf[1], kf1, a, 0, 0, 0);
            sc[ni] = a * 0.125f;
        }
        float alpha[4], rs[4];
#pragma unroll
        for (int r = 0; r < 4; r++) {
            float v = fmaxf(fmaxf(sc[0][r], sc[1][r]), fmaxf(sc[2][r], sc[3][r]));
            v = fmaxf(v, __shfl_xor(v, 1));
            v = fmaxf(v, __shfl_xor(v, 2));
            v = fmaxf(v, __shfl_xor(v, 4));
            v = fmaxf(v, __shfl_xor(v, 8));
            float mn = fmaxf(m_i[r], v);
            alpha[r] = __expf(m_i[r] - mn);
            m_i[r] = mn;
            rs[r] = 0.f;
        }
#pragma unroll
        for (int ni = 0; ni < 4; ni++)
#pragma unroll
            for (int r = 0; r < 4; r++) {
                float pv = __expf(sc[ni][r] - m_i[r]);
                sc[ni][r] = pv;
                rs[r] += pv;
            }
#pragma unroll
        for (int r = 0; r < 4; r++) {
            float v = rs[r];
            v += __shfl_xor(v, 1);
            v += __shfl_xor(v, 2);
            v += __shfl_xor(v, 4);
            v += __shfl_xor(v, 8);
            l_i[r] = l_i[r] * alpha[r] + v;
        }
#pragma unroll
        for (int ni = 0; ni < 4; ni++)
#pragma unroll
            for (int r = 0; r < 4; r++) {
                int row = quad * 4 + r;
                int key = ni * 16 + l15;
                int chn = ((key >> 3) ^ (row >> 3)) * 8 + (key & 7);
                Ps[wave][row * 72 + chn] = f2bf(sc[ni][r]);
            }
        __syncthreads();
#pragma unroll
        for (int ni = 0; ni < 4; ni++) {
            f4v t = o[ni];
            t[0] *= alpha[0]; t[1] *= alpha[1]; t[2] *= alpha[2]; t[3] *= alpha[3];
            o[ni] = t;
        }
        s8v pf0 = *(const s8v*)(&Ps[wave][l15 * 72 + ((quad ^ (l15 >> 3)) * 8)]);
        s8v pf1 = *(const s8v*)(&Ps[wave][l15 * 72 + (((4 + quad) ^ (l15 >> 3)) * 8)]);
#pragma unroll
        for (int ni = 0; ni < 4; ni++) {
            int d = ni * 16 + l15;
            s8v vf0 = *(const s8v*)(&Vt[d * 72 + ((quad ^ (d >> 3)) * 8)]);
            s8v vf1 = *(const s8v*)(&Vt[d * 72 + (((4 + quad) ^ (d >> 3)) * 8)]);
            o[ni] = __builtin_amdgcn_mfma_f32_16x16x32_bf16(pf0, vf0, o[ni], 0, 0, 0);
            o[ni] = __builtin_amdgcn_mfma_f32_16x16x32_bf16(pf1, vf1, o[ni], 0, 0, 0);
        }
    }
#pragma unroll
    for (int r = 0; r < 4; r++) {
        float inv = 1.0f / l_i[r];
        int srow = q0 + wave * 16 + quad * 4 + r;
        long obase = ((long)b * 2048 + srow) * 3072 + h * 64;
#pragma unroll
        for (int ni = 0; ni < 4; ni++)
            qkv[obase + ni * 16 + l15] = f2bf(o[ni][r] * inv);
    }
}

extern "C" void kernel_launch(void* const* d_in, const int* in_sizes, int n_in,
                              void* d_out, int out_size, void* d_ws, size_t ws_size,
                              hipStream_t stream) {
    (void)in_sizes; (void)n_in; (void)out_size;
    const float* x  = (const float*)d_in[0];
    const float* Wq = (const float*)d_in[1];
    const float* Wk = (const float*)d_in[2];
    const float* Wv = (const float*)d_in[3];
    const float* Wo = (const float*)d_in[4];

    const size_t need = 67108864ULL; // 64 MiB
    if (ws_size >= need) {
        short* xb    = (short*)d_ws;              // 4096x2048
        short* Wqkvt = xb + 8388608;              // 3072x2048
        short* Wot   = Wqkvt + 6291456;           // 2048x2048
        short* qkv   = Wot + 4194304;             // 4096x3072
        short* Vt_g  = qkv + 12582912;            // 16x64x2048

        cvt_x<<<4096, 256, 0, stream>>>(x, xb);
        cvt_wt<<<dim3(32, 32), 256, 0, stream>>>(Wq, Wqkvt, 2048, 0);
        cvt_wt<<<dim3(8, 32), 256, 0, stream>>>(Wk, Wqkvt, 512, 2048);
        cvt_wt<<<dim3(8, 32), 256, 0, stream>>>(Wv, Wqkvt, 512, 2560);
        cvt_wt<<<dim3(32, 32), 256, 0, stream>>>(Wo, Wot, 2048, 0);
        gemm_bt<false><<<dim3(24, 32), 256, 0, stream>>>(xb, Wqkvt, qkv, 2048, 2048, 2048, 3072);
        rope_kernel<<<dim3(20480), 256, 0, stream>>>(qkv);
        vtrans<<<dim3(32, 8, 2), 256, 0, stream>>>(qkv, Vt_g);
        attn3<<<dim3(32, 32, 2), 256, 0, stream>>>(qkv, Vt_g);
        gemm_bt<true><<<dim3(16, 32), 256, 0, stream>>>(qkv, Wot, d_out, 2048, 3072, 2048, 2048);
    } else {
        short* qkv = (short*)d_ws;
        gemm_bn<true, false><<<dim3(16, 32), 256, 0, stream>>>(x, Wq, qkv,        2048, 2048, 2048, 3072);
        gemm_bn<true, false><<<dim3(4, 32), 256, 0, stream>>>(x, Wk, qkv + 2048, 2048,  512, 2048, 3072);
        gemm_bn<true, false><<<dim3(4, 32), 256, 0, stream>>>(x, Wv, qkv + 2560, 2048,  512, 2048, 3072);
        rope_kernel<<<dim3(20480), 256, 0, stream>>>(qkv);
        attn_kernel<<<dim3(32, 32, 2), 256, 0, stream>>>(qkv);
        gemm_bn<false, true><<<dim3(16, 32), 256, 0, stream>>>(qkv, Wo, d_out, 2048, 2048, 3072, 2048);
    }
}